// Round 10
// baseline (390.928 us; speedup 1.0000x reference)
//
#include <hip/hip_runtime.h>
#include <math.h>

#define BATCH_ 65536
#define NN 512
#define KK 48
#define OFF_HHRE (2*BATCH_*KK)            // 6291456
#define OFF_HHIM (OFF_HHRE + BATCH_*NN)   // 39845888

typedef float f32x4 __attribute__((ext_vector_type(4)));
typedef int   i32x4 __attribute__((ext_vector_type(4)));
typedef short bf16x8 __attribute__((ext_vector_type(8)));

// ---- ws layout (byte offsets) ----
#define WS_FR    0u         // 16 chunks x 16384 B = 262144 B
#define WS_SIGP  262144u    // 256 f32
#define WS_SIGMA 263168u    // 1 f32
#define WS_BPART 264192u    // 4096*2 f32 = 32 KB
#define WS_BVAL  296960u    // 2 f32

__device__ __forceinline__ unsigned short f2bf(float x) {
  unsigned u = __builtin_bit_cast(unsigned, x);
  unsigned r = (u + 0x7fffu + ((u >> 16) & 1u)) >> 16;
  return (unsigned short)r;
}
// single-instruction packed f32->bf16 (RTNE, same as f2bf)
__device__ __forceinline__ int cvtpk(float lo, float hi) {
  int r;
  asm("v_cvt_pk_bf16_f32 %0, %1, %2" : "=v"(r) : "v"(lo), "v"(hi));
  return r;
}
__device__ __forceinline__ i32x4 pack8bf_pk(f32x4 a, f32x4 b) {
  i32x4 r;
  r.x = cvtpk(a.x, a.y); r.y = cvtpk(a.z, a.w);
  r.z = cvtpk(b.x, b.y); r.w = cvtpk(b.z, b.w);
  return r;
}
__device__ __forceinline__ float waveRed(float v) {
#pragma unroll
  for (int o = 32; o > 0; o >>= 1) v += __shfl_down(v, o);
  return v;
}

#define MFMA(acc, A, B) \
  acc = __builtin_amdgcn_mfma_f32_16x16x32_bf16( \
      __builtin_bit_cast(bf16x8, A), __builtin_bit_cast(bf16x8, B), acc, 0, 0, 0)

// ---------------- pack frag table (16 KB-strided pair-tile chunks) ---------
__global__ void lamp_pack(const float* __restrict__ Bre, const float* __restrict__ Bim,
                          const float* __restrict__ Are, const float* __restrict__ Aim,
                          unsigned short* __restrict__ fr)
{
  int i = blockIdx.x * 256 + threadIdx.x;       // 512*256 = 131072 = 16*8192
  int jj = i & 7, l = (i >> 3) & 63;
  int j = (i >> 9) & 15;                        // slot within chunk (0..15)
  int p = i >> 13;                              // chunk (0..15)
  float v = 0.f;
  if (j < 8) {
    int nt = 2*p + (j >> 2);
    int mat = (j >> 1) & 1;
    int ks = j & 1;
    int k = ks*32 + (l >> 4)*8 + jj;
    int n = nt*16 + (l & 15);
    v = (k < KK) ? (mat ? Bim[n*KK + k] : Bre[n*KK + k]) : 0.f;
  } else if (j < 14) {
    int jp = j - 8;
    int ct = jp >> 1, m = jp & 1;
    int k = p*32 + (l >> 4)*8 + jj;
    int c = ct*16 + (l & 15);
    v = m ? Aim[k*KK + c] : Are[k*KK + c];
  }
  fr[i] = f2bf(v);
}

// ---------------- sigma ----------------
__global__ void lamp_sig(const float* __restrict__ zr, const float* __restrict__ zi,
                         float* __restrict__ part)
{
  const int n4 = BATCH_*KK/4;
  const f32x4* a = (const f32x4*)zr; const f32x4* b = (const f32x4*)zi;
  float s = 0.f;
  for (int i = blockIdx.x*blockDim.x + threadIdx.x; i < n4; i += gridDim.x*blockDim.x) {
    f32x4 x = a[i]; s += x.x*x.x + x.y*x.y + x.z*x.z + x.w*x.w;
    f32x4 y = b[i]; s += y.x*y.x + y.y*y.y + y.z*y.z + y.w*y.w;
  }
  __shared__ float red[4];
  s = waveRed(s);
  int wave = threadIdx.x >> 6, lane = threadIdx.x & 63;
  if (lane == 0) red[wave] = s;
  __syncthreads();
  if (threadIdx.x == 0) part[blockIdx.x] = red[0]+red[1]+red[2]+red[3];
}

__global__ void lamp_sigfin(const float* __restrict__ part, float* __restrict__ sig)
{
  float s = part[threadIdx.x];   // 256 partials
  __shared__ float red[4];
  s = waveRed(s);
  int wave = threadIdx.x >> 6, lane = threadIdx.x & 63;
  if (lane == 0) red[wave] = s;
  __syncthreads();
  if (threadIdx.x == 0) sig[0] = sqrtf(red[0]+red[1]+red[2]+red[3]) / sqrtf((float)KK);
}

// ---------------- main fused kernel (R10) ----------------------------------
// MODE 0 = full (real output). MODE 2 = ablation probe: no shuffle/pack/GEMM2
// (and none of its ds_reads). NITER = loop count (probe runs 32 for top-5
// visibility; p wraps, harmless — probe output is overwritten by the MODE-0
// dispatch that follows it).
// R10 changes vs R9: v_cvt_pk_bf16_f32 packing, plain (non-NT) Hh stores,
// s_setprio(1) around MFMA clusters.
template<int MODE, int NITER>
__global__ __launch_bounds__(256, 3) void lamp_main(
    const float* __restrict__ zre, const float* __restrict__ zim,
    const float* __restrict__ Hre, const float* __restrict__ Him,
    const unsigned short* __restrict__ fr,
    const float* __restrict__ sigp, const float* __restrict__ theta,
    float* __restrict__ out, float* __restrict__ bpart)
{
  __shared__ __align__(16) i32x4 fb[2][1024];   // 2 x 16384 B

  const int tid = threadIdx.x;
  const int wave = tid >> 6, lane = tid & 63;
  const int l15 = lane & 15, lg = lane >> 4;
  const int rbase = blockIdx.x * 64 + wave * 16;
  const int myrow = rbase + l15;
  const int phase = blockIdx.x & 15;
  const char* frc = (const char*)fr;

#define STAGE(bi, pp) do { \
    const char* gsrc_ = frc + (size_t)(pp)*16384 + wave*4096 + lane*16; \
    char* ldst_ = ((char*)&fb[bi][0]) + wave*4096 + lane*16; \
    _Pragma("unroll") \
    for (int s_ = 0; s_ < 4; ++s_) \
      __builtin_amdgcn_global_load_lds( \
          (const __attribute__((address_space(1))) void*)(gsrc_ + s_*1024), \
          (__attribute__((address_space(3))) void*)(ldst_ + s_*1024), 16, 0, 0); \
    asm volatile("" ::: "memory"); \
  } while (0)

  const float t0 = theta[0], t1 = theta[1], t2 = theta[2];
  const float sigma = sigp[0];
  const float s2 = (t0 * sigma) * (t0 * sigma);
  const float inv_s2 = 1.0f / s2;
  const float nhalf_inv_s2 = -0.5f * inv_s2;

  // z fragments (B operand of GEMM1'), K padded 48->64
  i32x4 zr[2], zi[2];
  {
    const float* pr = zre + (size_t)myrow * KK;
    const float* pi = zim + (size_t)myrow * KK;
#pragma unroll
    for (int ks = 0; ks < 2; ++ks) {
      const int k0 = ks*32 + lg*8;
      f32x4 a0 = {0,0,0,0}, a1 = {0,0,0,0}, b0 = {0,0,0,0}, b1 = {0,0,0,0};
      if (k0 < KK) {
        a0 = *(const f32x4*)(pr + k0); a1 = *(const f32x4*)(pr + k0 + 4);
        b0 = *(const f32x4*)(pi + k0); b1 = *(const f32x4*)(pi + k0 + 4);
      }
      zr[ks] = pack8bf_pk(a0, a1);
      zi[ks] = pack8bf_pk(b0, b1);
    }
  }

  const float* hrB = Hre + (size_t)myrow * NN + lg*4;
  const float* hiB = Him + (size_t)myrow * NN + lg*4;
  float* oRB = out + OFF_HHRE + (size_t)myrow * NN + lg*4;
  float* oIB = out + OFF_HHIM + (size_t)myrow * NN + lg*4;

  f32x4 ahR[3], ahI[3];
#pragma unroll
  for (int c = 0; c < 3; ++c) { ahR[c] = (f32x4){0,0,0,0}; ahI[c] = (f32x4){0,0,0,0}; }

  float dsr = 0.f, dsi = 0.f;
  const bool hi2 = (lg >= 2);
  const int srcA = l15 + ((lane & 16) << 1);
  const int srcB = srcA + 16;

  // prologue: stage chunk for t=0, full drain once
  STAGE(0, phase);
  asm volatile("s_waitcnt vmcnt(0)" ::: "memory");
  __builtin_amdgcn_s_barrier();

#pragma unroll 1
  for (int t = 0; t < NITER; ++t) {
    const int cur = t & 1;
    const int p = (phase + t) & 15;

    // H loads first (deepest latency)
    f32x4 hR0 = *(const f32x4*)(hrB + 32*p);
    f32x4 hR1 = *(const f32x4*)(hrB + 32*p + 16);
    f32x4 hI0 = *(const f32x4*)(hiB + 32*p);
    f32x4 hI1 = *(const f32x4*)(hiB + 32*p + 16);

    if (t < NITER-1) STAGE(cur ^ 1, (phase + t + 1) & 15);

    const i32x4* fbc = &fb[cur][0];
    i32x4 nzi0 = zi[0] ^ 0x80008000, nzi1 = zi[1] ^ 0x80008000;

    // ---- GEMM1' tiles (frags from LDS) ----
    f32x4 aR0 = (f32x4){0,0,0,0}, aI0 = (f32x4){0,0,0,0};
    f32x4 aR1 = (f32x4){0,0,0,0}, aI1 = (f32x4){0,0,0,0};
    {
      i32x4 b0 = fbc[0*64 + lane];
      i32x4 b1 = fbc[1*64 + lane];
      i32x4 c0 = fbc[2*64 + lane];
      i32x4 c1 = fbc[3*64 + lane];
      i32x4 d0 = fbc[4*64 + lane];
      i32x4 d1 = fbc[5*64 + lane];
      i32x4 e0 = fbc[6*64 + lane];
      i32x4 e1 = fbc[7*64 + lane];
      __builtin_amdgcn_s_setprio(1);
      MFMA(aR0, b0, zr[0]); MFMA(aR0, b1, zr[1]);
      MFMA(aR0, c0, nzi0);  MFMA(aR0, c1, nzi1);
      MFMA(aI0, b0, zi[0]); MFMA(aI0, b1, zi[1]);
      MFMA(aI0, c0, zr[0]); MFMA(aI0, c1, zr[1]);
      MFMA(aR1, d0, zr[0]); MFMA(aR1, d1, zr[1]);
      MFMA(aR1, e0, nzi0);  MFMA(aR1, e1, nzi1);
      MFMA(aI1, d0, zi[0]); MFMA(aI1, d1, zi[1]);
      MFMA(aI1, e0, zr[0]); MFMA(aI1, e1, zr[1]);
      __builtin_amdgcn_s_setprio(0);
    }

    // ---- fused elementwise: R = H + Z, shrink, deriv ----
    f32x4 re0 = aR0 + hR0, im0 = aI0 + hI0;
    f32x4 re1 = aR1 + hR1, im1 = aI1 + hI1;
    f32x4 hhr0, hhi0, hhr1, hhi1;
#pragma unroll
    for (int c = 0; c < 4; ++c) {
      float x;
      x = re0[c]; { float e = __expf(x*x*nhalf_inv_s2); float te = t2*e;
        hhr0[c] = t1*x + x*te; dsr += t1 + te*(1.f - x*x*inv_s2); }
      x = im0[c]; { float e = __expf(x*x*nhalf_inv_s2); float te = t2*e;
        hhi0[c] = t1*x + x*te; dsi += t1 + te*(1.f - x*x*inv_s2); }
      x = re1[c]; { float e = __expf(x*x*nhalf_inv_s2); float te = t2*e;
        hhr1[c] = t1*x + x*te; dsr += t1 + te*(1.f - x*x*inv_s2); }
      x = im1[c]; { float e = __expf(x*x*nhalf_inv_s2); float te = t2*e;
        hhi1[c] = t1*x + x*te; dsi += t1 + te*(1.f - x*x*inv_s2); }
    }

    if constexpr (MODE != 2) {
      // ---- 4-lane exchange: acc row-slices -> GEMM2' B-operand frags ----
      f32x4 selR, selI;
#pragma unroll
      for (int c = 0; c < 4; ++c) {
        selR[c] = hi2 ? hhr1[c] : hhr0[c];
        selI[c] = hi2 ? hhi1[c] : hhi0[c];
      }
      f32x4 w0, w1, v0, v1;
#pragma unroll
      for (int c = 0; c < 4; ++c) {
        w0[c] = __shfl(selR[c], srcA, 64);
        w1[c] = __shfl(selR[c], srcB, 64);
        v0[c] = __shfl(selI[c], srcA, 64);
        v1[c] = __shfl(selI[c], srcB, 64);
      }
      i32x4 hhRf = pack8bf_pk(w0, w1);
      i32x4 hhIf = pack8bf_pk(v0, v1);

      // ---- GEMM2' partial: k-slice p ----
      __builtin_amdgcn_s_setprio(1);
#pragma unroll
      for (int ct = 0; ct < 3; ++ct) {
        i32x4 par = fbc[(8 + 2*ct)*64 + lane];
        i32x4 pai = fbc[(9 + 2*ct)*64 + lane];
        i32x4 nai = pai ^ 0x80008000;
        MFMA(ahR[ct], par, hhRf);
        MFMA(ahR[ct], nai, hhIf);
        MFMA(ahI[ct], pai, hhRf);
        MFMA(ahI[ct], par, hhIf);
      }
      __builtin_amdgcn_s_setprio(0);
    }

    // ---- Hh stores LAST in VMEM order (plain stores: L2 write-back) ----
    *(f32x4*)(oRB + 32*p)      = hhr0;
    *(f32x4*)(oRB + 32*p + 16) = hhr1;
    *(f32x4*)(oIB + 32*p)      = hhi0;
    *(f32x4*)(oIB + 32*p + 16) = hhi1;

    // counted barrier: wait for stage (and older), NOT this iter's 4 stores
    asm volatile("s_waitcnt vmcnt(4)" ::: "memory");
    __builtin_amdgcn_s_barrier();
    __builtin_amdgcn_sched_barrier(0);
  }

  // epilogue: h stored as per-lane f32x4 row slices
#pragma unroll
  for (int ct = 0; ct < 3; ++ct) {
    *(f32x4*)(out + (size_t)myrow*KK + ct*16 + lg*4) = ahR[ct];
    *(f32x4*)(out + (size_t)(BATCH_*KK) + (size_t)myrow*KK + ct*16 + lg*4) = ahI[ct];
  }

  float rr = waveRed(dsr), ri = waveRed(dsi);
  if (lane == 0) {
    const int w = blockIdx.x * 4 + wave;
    bpart[2*w]     = rr;
    bpart[2*w + 1] = ri;
  }
#undef STAGE
}

// ---------------- b reduce (4096 wave-partials) ----------------
__global__ void lamp_bred(const float* __restrict__ bpart, float* __restrict__ bval)
{
  float sr = 0.f, si = 0.f;
  for (int m = threadIdx.x; m < 4096; m += 256) { sr += bpart[2*m]; si += bpart[2*m + 1]; }
  __shared__ float red[8];
  sr = waveRed(sr); si = waveRed(si);
  int wave = threadIdx.x >> 6, lane = threadIdx.x & 63;
  if (lane == 0) { red[wave] = sr; red[4 + wave] = si; }
  __syncthreads();
  if (threadIdx.x == 0) {
    bval[0] = (red[0]+red[1]+red[2]+red[3]) / (float)KK;
    bval[1] = (red[4]+red[5]+red[6]+red[7]) / (float)KK;
  }
}

// ---------------- z_new (in-place over parked h) ----------------
__global__ void lamp_znew(const float* __restrict__ ur, const float* __restrict__ ui,
                          const float* __restrict__ zr, const float* __restrict__ zi,
                          const float* __restrict__ bval, float* __restrict__ out)
{
  const float br = bval[0], bi = bval[1];
  const int n4 = BATCH_*KK/4;
  const f32x4* u4r = (const f32x4*)ur; const f32x4* u4i = (const f32x4*)ui;
  const f32x4* z4r = (const f32x4*)zr; const f32x4* z4i = (const f32x4*)zi;
  f32x4* o4r = (f32x4*)out;
  f32x4* o4i = (f32x4*)(out + BATCH_*KK);
  for (int i = blockIdx.x*blockDim.x + threadIdx.x; i < n4; i += gridDim.x*blockDim.x) {
    f32x4 h = o4r[i];
    o4r[i] = u4r[i] - h + br * z4r[i];
    f32x4 h2 = o4i[i];
    o4i[i] = u4i[i] - h2 + bi * z4i[i];
  }
}

extern "C" void kernel_launch(void* const* d_in, const int* in_sizes, int n_in,
                              void* d_out, int out_size, void* d_ws, size_t ws_size,
                              hipStream_t stream)
{
  const float* ur  = (const float*)d_in[0];
  const float* ui  = (const float*)d_in[1];
  const float* zr  = (const float*)d_in[2];
  const float* zi  = (const float*)d_in[3];
  const float* Hr  = (const float*)d_in[4];
  const float* Hi  = (const float*)d_in[5];
  const float* Bre = (const float*)d_in[6];
  const float* Bim = (const float*)d_in[7];
  const float* Are = (const float*)d_in[8];
  const float* Aim = (const float*)d_in[9];
  const float* th  = (const float*)d_in[10];
  float* out = (float*)d_out;
  char* ws = (char*)d_ws;
  unsigned short* fr = (unsigned short*)(ws + WS_FR);
  float* sigp  = (float*)(ws + WS_SIGP);
  float* sigv  = (float*)(ws + WS_SIGMA);
  float* bpart = (float*)(ws + WS_BPART);
  float* bval  = (float*)(ws + WS_BVAL);

  hipLaunchKernelGGL(lamp_pack,   dim3(512),  dim3(256), 0, stream, Bre, Bim, Are, Aim, fr);
  hipLaunchKernelGGL(lamp_sig,    dim3(256),  dim3(256), 0, stream, zr, zi, sigp);
  hipLaunchKernelGGL(lamp_sigfin, dim3(1),    dim3(256), 0, stream, sigp, sigv);

  // ---- ablation probe (MODE 2, 32 iters): output scratch, fully
  // overwritten by the real MODE-0 dispatch below. Timing read from rocprof.
  hipLaunchKernelGGL((lamp_main<2,32>), dim3(1024), dim3(256), 0, stream,
                     zr, zi, Hr, Hi, fr, sigv, th, out, bpart);

  // ---- real dispatch ----
  hipLaunchKernelGGL((lamp_main<0,16>), dim3(1024), dim3(256), 0, stream,
                     zr, zi, Hr, Hi, fr, sigv, th, out, bpart);

  hipLaunchKernelGGL(lamp_bred,   dim3(1),    dim3(256), 0, stream, bpart, bval);
  hipLaunchKernelGGL(lamp_znew,   dim3(1024), dim3(256), 0, stream, ur, ui, zr, zi, bval, out);
}

// Round 11
// 180.515 us; speedup vs baseline: 2.1656x; 2.1656x over previous
//
#include <hip/hip_runtime.h>
#include <math.h>

#define BATCH_ 65536
#define NN 512
#define KK 48
#define OFF_HHRE (2*BATCH_*KK)            // 6291456
#define OFF_HHIM (OFF_HHRE + BATCH_*NN)   // 39845888

typedef float f32x4 __attribute__((ext_vector_type(4)));
typedef int   i32x4 __attribute__((ext_vector_type(4)));
typedef short bf16x8 __attribute__((ext_vector_type(8)));

// ---- ws layout (byte offsets) ----
#define WS_FR    0u         // 16 chunks x 16384 B = 262144 B
#define WS_SIGP  262144u    // 256 f32
#define WS_SIGMA 263168u    // 1 f32
#define WS_BPART 264192u    // 4096*2 f32 = 32 KB
#define WS_BVAL  296960u    // 2 f32

__device__ __forceinline__ unsigned short f2bf(float x) {
  unsigned u = __builtin_bit_cast(unsigned, x);
  unsigned r = (u + 0x7fffu + ((u >> 16) & 1u)) >> 16;
  return (unsigned short)r;
}
// single-instruction packed f32->bf16 (RTNE, same as f2bf)
__device__ __forceinline__ int cvtpk(float lo, float hi) {
  int r;
  asm("v_cvt_pk_bf16_f32 %0, %1, %2" : "=v"(r) : "v"(lo), "v"(hi));
  return r;
}
__device__ __forceinline__ i32x4 pack8bf_pk(f32x4 a, f32x4 b) {
  i32x4 r;
  r.x = cvtpk(a.x, a.y); r.y = cvtpk(a.z, a.w);
  r.z = cvtpk(b.x, b.y); r.w = cvtpk(b.z, b.w);
  return r;
}
__device__ __forceinline__ float waveRed(float v) {
#pragma unroll
  for (int o = 32; o > 0; o >>= 1) v += __shfl_down(v, o);
  return v;
}

#define MFMA(acc, A, B) \
  acc = __builtin_amdgcn_mfma_f32_16x16x32_bf16( \
      __builtin_bit_cast(bf16x8, A), __builtin_bit_cast(bf16x8, B), acc, 0, 0, 0)

// ---------------- pack frag table (16 KB-strided pair-tile chunks) ---------
__global__ void lamp_pack(const float* __restrict__ Bre, const float* __restrict__ Bim,
                          const float* __restrict__ Are, const float* __restrict__ Aim,
                          unsigned short* __restrict__ fr)
{
  int i = blockIdx.x * 256 + threadIdx.x;       // 512*256 = 131072 = 16*8192
  int jj = i & 7, l = (i >> 3) & 63;
  int j = (i >> 9) & 15;                        // slot within chunk (0..15)
  int p = i >> 13;                              // chunk (0..15)
  float v = 0.f;
  if (j < 8) {
    int nt = 2*p + (j >> 2);
    int mat = (j >> 1) & 1;
    int ks = j & 1;
    int k = ks*32 + (l >> 4)*8 + jj;
    int n = nt*16 + (l & 15);
    v = (k < KK) ? (mat ? Bim[n*KK + k] : Bre[n*KK + k]) : 0.f;
  } else if (j < 14) {
    int jp = j - 8;
    int ct = jp >> 1, m = jp & 1;
    int k = p*32 + (l >> 4)*8 + jj;
    int c = ct*16 + (l & 15);
    v = m ? Aim[k*KK + c] : Are[k*KK + c];
  }
  fr[i] = f2bf(v);
}

// ---------------- sigma ----------------
__global__ void lamp_sig(const float* __restrict__ zr, const float* __restrict__ zi,
                         float* __restrict__ part)
{
  const int n4 = BATCH_*KK/4;
  const f32x4* a = (const f32x4*)zr; const f32x4* b = (const f32x4*)zi;
  float s = 0.f;
  for (int i = blockIdx.x*blockDim.x + threadIdx.x; i < n4; i += gridDim.x*blockDim.x) {
    f32x4 x = a[i]; s += x.x*x.x + x.y*x.y + x.z*x.z + x.w*x.w;
    f32x4 y = b[i]; s += y.x*y.x + y.y*y.y + y.z*y.z + y.w*y.w;
  }
  __shared__ float red[4];
  s = waveRed(s);
  int wave = threadIdx.x >> 6, lane = threadIdx.x & 63;
  if (lane == 0) red[wave] = s;
  __syncthreads();
  if (threadIdx.x == 0) part[blockIdx.x] = red[0]+red[1]+red[2]+red[3];
}

__global__ void lamp_sigfin(const float* __restrict__ part, float* __restrict__ sig)
{
  float s = part[threadIdx.x];   // 256 partials
  __shared__ float red[4];
  s = waveRed(s);
  int wave = threadIdx.x >> 6, lane = threadIdx.x & 63;
  if (lane == 0) red[wave] = s;
  __syncthreads();
  if (threadIdx.x == 0) sig[0] = sqrtf(red[0]+red[1]+red[2]+red[3]) / sqrtf((float)KK);
}

// ---------------- main fused kernel (R11) ----------------------------------
// R10 structure (LDS frag staging, counted vmcnt barrier, cvt_pk, plain
// stores, setprio) + H-prefetch distance 1: iteration t issues the H loads
// for t+1 first (deepest latency), consumes registers loaded last iteration.
// Unroll-by-2 with two NAMED register sets (runtime-indexed arrays would
// spill to scratch). Probe removed (R10 ablation: back half is free; front
// H-chain + VMEM stream is the binding resource).
__global__ __launch_bounds__(256, 3) void lamp_main(
    const float* __restrict__ zre, const float* __restrict__ zim,
    const float* __restrict__ Hre, const float* __restrict__ Him,
    const unsigned short* __restrict__ fr,
    const float* __restrict__ sigp, const float* __restrict__ theta,
    float* __restrict__ out, float* __restrict__ bpart)
{
  __shared__ __align__(16) i32x4 fb[2][1024];   // 2 x 16384 B

  const int tid = threadIdx.x;
  const int wave = tid >> 6, lane = tid & 63;
  const int l15 = lane & 15, lg = lane >> 4;
  const int rbase = blockIdx.x * 64 + wave * 16;
  const int myrow = rbase + l15;
  const int phase = blockIdx.x & 15;
  const char* frc = (const char*)fr;

#define STAGE(bi, pp) do { \
    const char* gsrc_ = frc + (size_t)(pp)*16384 + wave*4096 + lane*16; \
    char* ldst_ = ((char*)&fb[bi][0]) + wave*4096 + lane*16; \
    _Pragma("unroll") \
    for (int s_ = 0; s_ < 4; ++s_) \
      __builtin_amdgcn_global_load_lds( \
          (const __attribute__((address_space(1))) void*)(gsrc_ + s_*1024), \
          (__attribute__((address_space(3))) void*)(ldst_ + s_*1024), 16, 0, 0); \
    asm volatile("" ::: "memory"); \
  } while (0)

  const float t0 = theta[0], t1 = theta[1], t2 = theta[2];
  const float sigma = sigp[0];
  const float s2 = (t0 * sigma) * (t0 * sigma);
  const float inv_s2 = 1.0f / s2;
  const float nhalf_inv_s2 = -0.5f * inv_s2;

  // z fragments (B operand of GEMM1'), K padded 48->64
  i32x4 zr[2], zi[2];
  {
    const float* pr = zre + (size_t)myrow * KK;
    const float* pi = zim + (size_t)myrow * KK;
#pragma unroll
    for (int ks = 0; ks < 2; ++ks) {
      const int k0 = ks*32 + lg*8;
      f32x4 a0 = {0,0,0,0}, a1 = {0,0,0,0}, b0 = {0,0,0,0}, b1 = {0,0,0,0};
      if (k0 < KK) {
        a0 = *(const f32x4*)(pr + k0); a1 = *(const f32x4*)(pr + k0 + 4);
        b0 = *(const f32x4*)(pi + k0); b1 = *(const f32x4*)(pi + k0 + 4);
      }
      zr[ks] = pack8bf_pk(a0, a1);
      zi[ks] = pack8bf_pk(b0, b1);
    }
  }

  const float* hrB = Hre + (size_t)myrow * NN + lg*4;
  const float* hiB = Him + (size_t)myrow * NN + lg*4;
  float* oRB = out + OFF_HHRE + (size_t)myrow * NN + lg*4;
  float* oIB = out + OFF_HHIM + (size_t)myrow * NN + lg*4;

  f32x4 ahR[3], ahI[3];
#pragma unroll
  for (int c = 0; c < 3; ++c) { ahR[c] = (f32x4){0,0,0,0}; ahI[c] = (f32x4){0,0,0,0}; }

  float dsr = 0.f, dsi = 0.f;
  const bool hi2 = (lg >= 2);
  const int srcA = l15 + ((lane & 16) << 1);
  const int srcB = srcA + 16;

  // one iteration body: consumes H regs (c-set), prefetches into n-set.
#define BODY(t_, hR0c,hR1c,hI0c,hI1c, hR0n,hR1n,hI0n,hI1n) do { \
    const int p_ = (phase + (t_)) & 15; \
    if ((t_) < 15) { \
      const int pn_ = (phase + (t_) + 1) & 15; \
      hR0n = *(const f32x4*)(hrB + 32*pn_); \
      hR1n = *(const f32x4*)(hrB + 32*pn_ + 16); \
      hI0n = *(const f32x4*)(hiB + 32*pn_); \
      hI1n = *(const f32x4*)(hiB + 32*pn_ + 16); \
      STAGE(((t_) + 1) & 1, pn_); \
    } \
    const i32x4* fbc = &fb[(t_) & 1][0]; \
    i32x4 nzi0 = zi[0] ^ 0x80008000, nzi1 = zi[1] ^ 0x80008000; \
    f32x4 aR0 = (f32x4){0,0,0,0}, aI0 = (f32x4){0,0,0,0}; \
    f32x4 aR1 = (f32x4){0,0,0,0}, aI1 = (f32x4){0,0,0,0}; \
    { \
      i32x4 b0 = fbc[0*64 + lane]; \
      i32x4 b1 = fbc[1*64 + lane]; \
      i32x4 c0 = fbc[2*64 + lane]; \
      i32x4 c1 = fbc[3*64 + lane]; \
      i32x4 d0 = fbc[4*64 + lane]; \
      i32x4 d1 = fbc[5*64 + lane]; \
      i32x4 e0 = fbc[6*64 + lane]; \
      i32x4 e1 = fbc[7*64 + lane]; \
      __builtin_amdgcn_s_setprio(1); \
      MFMA(aR0, b0, zr[0]); MFMA(aR0, b1, zr[1]); \
      MFMA(aR0, c0, nzi0);  MFMA(aR0, c1, nzi1); \
      MFMA(aI0, b0, zi[0]); MFMA(aI0, b1, zi[1]); \
      MFMA(aI0, c0, zr[0]); MFMA(aI0, c1, zr[1]); \
      MFMA(aR1, d0, zr[0]); MFMA(aR1, d1, zr[1]); \
      MFMA(aR1, e0, nzi0);  MFMA(aR1, e1, nzi1); \
      MFMA(aI1, d0, zi[0]); MFMA(aI1, d1, zi[1]); \
      MFMA(aI1, e0, zr[0]); MFMA(aI1, e1, zr[1]); \
      __builtin_amdgcn_s_setprio(0); \
    } \
    f32x4 re0 = aR0 + hR0c, im0 = aI0 + hI0c; \
    f32x4 re1 = aR1 + hR1c, im1 = aI1 + hI1c; \
    f32x4 hhr0, hhi0, hhr1, hhi1; \
    _Pragma("unroll") \
    for (int c = 0; c < 4; ++c) { \
      float x; \
      x = re0[c]; { float e = __expf(x*x*nhalf_inv_s2); float te = t2*e; \
        hhr0[c] = t1*x + x*te; dsr += t1 + te*(1.f - x*x*inv_s2); } \
      x = im0[c]; { float e = __expf(x*x*nhalf_inv_s2); float te = t2*e; \
        hhi0[c] = t1*x + x*te; dsi += t1 + te*(1.f - x*x*inv_s2); } \
      x = re1[c]; { float e = __expf(x*x*nhalf_inv_s2); float te = t2*e; \
        hhr1[c] = t1*x + x*te; dsr += t1 + te*(1.f - x*x*inv_s2); } \
      x = im1[c]; { float e = __expf(x*x*nhalf_inv_s2); float te = t2*e; \
        hhi1[c] = t1*x + x*te; dsi += t1 + te*(1.f - x*x*inv_s2); } \
    } \
    { \
      f32x4 selR, selI; \
      _Pragma("unroll") \
      for (int c = 0; c < 4; ++c) { \
        selR[c] = hi2 ? hhr1[c] : hhr0[c]; \
        selI[c] = hi2 ? hhi1[c] : hhi0[c]; \
      } \
      f32x4 w0, w1, v0, v1; \
      _Pragma("unroll") \
      for (int c = 0; c < 4; ++c) { \
        w0[c] = __shfl(selR[c], srcA, 64); \
        w1[c] = __shfl(selR[c], srcB, 64); \
        v0[c] = __shfl(selI[c], srcA, 64); \
        v1[c] = __shfl(selI[c], srcB, 64); \
      } \
      i32x4 hhRf = pack8bf_pk(w0, w1); \
      i32x4 hhIf = pack8bf_pk(v0, v1); \
      __builtin_amdgcn_s_setprio(1); \
      _Pragma("unroll") \
      for (int ct = 0; ct < 3; ++ct) { \
        i32x4 par = fbc[(8 + 2*ct)*64 + lane]; \
        i32x4 pai = fbc[(9 + 2*ct)*64 + lane]; \
        i32x4 nai = pai ^ 0x80008000; \
        MFMA(ahR[ct], par, hhRf); \
        MFMA(ahR[ct], nai, hhIf); \
        MFMA(ahI[ct], pai, hhRf); \
        MFMA(ahI[ct], par, hhIf); \
      } \
      __builtin_amdgcn_s_setprio(0); \
    } \
    asm volatile("" ::: "memory"); \
    *(f32x4*)(oRB + 32*p_)      = hhr0; \
    *(f32x4*)(oRB + 32*p_ + 16) = hhr1; \
    *(f32x4*)(oIB + 32*p_)      = hhi0; \
    *(f32x4*)(oIB + 32*p_ + 16) = hhi1; \
    asm volatile("s_waitcnt vmcnt(4)" ::: "memory"); \
    __builtin_amdgcn_s_barrier(); \
    __builtin_amdgcn_sched_barrier(0); \
  } while (0)

  // prologue: H regs for t=0 + stage chunk 0, full drain once
  f32x4 hR0a, hR1a, hI0a, hI1a, hR0b, hR1b, hI0b, hI1b;
  hR0a = *(const f32x4*)(hrB + 32*phase);
  hR1a = *(const f32x4*)(hrB + 32*phase + 16);
  hI0a = *(const f32x4*)(hiB + 32*phase);
  hI1a = *(const f32x4*)(hiB + 32*phase + 16);
  STAGE(0, phase);
  asm volatile("s_waitcnt vmcnt(0)" ::: "memory");
  __builtin_amdgcn_s_barrier();

#pragma unroll 1
  for (int t = 0; t < 16; t += 2) {
    BODY(t,     hR0a,hR1a,hI0a,hI1a, hR0b,hR1b,hI0b,hI1b);
    BODY(t + 1, hR0b,hR1b,hI0b,hI1b, hR0a,hR1a,hI0a,hI1a);
  }

  // epilogue: h stored as per-lane f32x4 row slices
#pragma unroll
  for (int ct = 0; ct < 3; ++ct) {
    *(f32x4*)(out + (size_t)myrow*KK + ct*16 + lg*4) = ahR[ct];
    *(f32x4*)(out + (size_t)(BATCH_*KK) + (size_t)myrow*KK + ct*16 + lg*4) = ahI[ct];
  }

  float rr = waveRed(dsr), ri = waveRed(dsi);
  if (lane == 0) {
    const int w = blockIdx.x * 4 + wave;
    bpart[2*w]     = rr;
    bpart[2*w + 1] = ri;
  }
#undef BODY
#undef STAGE
}

// ---------------- b reduce (4096 wave-partials) ----------------
__global__ void lamp_bred(const float* __restrict__ bpart, float* __restrict__ bval)
{
  float sr = 0.f, si = 0.f;
  for (int m = threadIdx.x; m < 4096; m += 256) { sr += bpart[2*m]; si += bpart[2*m + 1]; }
  __shared__ float red[8];
  sr = waveRed(sr); si = waveRed(si);
  int wave = threadIdx.x >> 6, lane = threadIdx.x & 63;
  if (lane == 0) { red[wave] = sr; red[4 + wave] = si; }
  __syncthreads();
  if (threadIdx.x == 0) {
    bval[0] = (red[0]+red[1]+red[2]+red[3]) / (float)KK;
    bval[1] = (red[4]+red[5]+red[6]+red[7]) / (float)KK;
  }
}

// ---------------- z_new (in-place over parked h) ----------------
__global__ void lamp_znew(const float* __restrict__ ur, const float* __restrict__ ui,
                          const float* __restrict__ zr, const float* __restrict__ zi,
                          const float* __restrict__ bval, float* __restrict__ out)
{
  const float br = bval[0], bi = bval[1];
  const int n4 = BATCH_*KK/4;
  const f32x4* u4r = (const f32x4*)ur; const f32x4* u4i = (const f32x4*)ui;
  const f32x4* z4r = (const f32x4*)zr; const f32x4* z4i = (const f32x4*)zi;
  f32x4* o4r = (f32x4*)out;
  f32x4* o4i = (f32x4*)(out + BATCH_*KK);
  for (int i = blockIdx.x*blockDim.x + threadIdx.x; i < n4; i += gridDim.x*blockDim.x) {
    f32x4 h = o4r[i];
    o4r[i] = u4r[i] - h + br * z4r[i];
    f32x4 h2 = o4i[i];
    o4i[i] = u4i[i] - h2 + bi * z4i[i];
  }
}

extern "C" void kernel_launch(void* const* d_in, const int* in_sizes, int n_in,
                              void* d_out, int out_size, void* d_ws, size_t ws_size,
                              hipStream_t stream)
{
  const float* ur  = (const float*)d_in[0];
  const float* ui  = (const float*)d_in[1];
  const float* zr  = (const float*)d_in[2];
  const float* zi  = (const float*)d_in[3];
  const float* Hr  = (const float*)d_in[4];
  const float* Hi  = (const float*)d_in[5];
  const float* Bre = (const float*)d_in[6];
  const float* Bim = (const float*)d_in[7];
  const float* Are = (const float*)d_in[8];
  const float* Aim = (const float*)d_in[9];
  const float* th  = (const float*)d_in[10];
  float* out = (float*)d_out;
  char* ws = (char*)d_ws;
  unsigned short* fr = (unsigned short*)(ws + WS_FR);
  float* sigp  = (float*)(ws + WS_SIGP);
  float* sigv  = (float*)(ws + WS_SIGMA);
  float* bpart = (float*)(ws + WS_BPART);
  float* bval  = (float*)(ws + WS_BVAL);

  hipLaunchKernelGGL(lamp_pack,   dim3(512),  dim3(256), 0, stream, Bre, Bim, Are, Aim, fr);
  hipLaunchKernelGGL(lamp_sig,    dim3(256),  dim3(256), 0, stream, zr, zi, sigp);
  hipLaunchKernelGGL(lamp_sigfin, dim3(1),    dim3(256), 0, stream, sigp, sigv);
  hipLaunchKernelGGL(lamp_main,   dim3(1024), dim3(256), 0, stream,
                     zr, zi, Hr, Hi, fr, sigv, th, out, bpart);
  hipLaunchKernelGGL(lamp_bred,   dim3(1),    dim3(256), 0, stream, bpart, bval);
  hipLaunchKernelGGL(lamp_znew,   dim3(1024), dim3(256), 0, stream, ur, ui, zr, zi, bval, out);
}

// Round 12
// 165.519 us; speedup vs baseline: 2.3618x; 1.0906x over previous
//
#include <hip/hip_runtime.h>
#include <math.h>

#define BATCH_ 65536
#define NN 512
#define KK 48
#define OFF_HHRE (2*BATCH_*KK)            // 6291456
#define OFF_HHIM (OFF_HHRE + BATCH_*NN)   // 39845888

typedef float f32x4 __attribute__((ext_vector_type(4)));
typedef int   i32x4 __attribute__((ext_vector_type(4)));
typedef short bf16x8 __attribute__((ext_vector_type(8)));

// ---- ws layout (byte offsets) ----
#define WS_FR    0u         // 16 chunks x 16384 B = 262144 B
#define WS_SIGP  262144u    // 256 f32
#define WS_SIGMA 263168u    // 1 f32
#define WS_BPART 264192u    // 4096*2 f32 = 32 KB
#define WS_BVAL  296960u    // 2 f32

__device__ __forceinline__ unsigned short f2bf(float x) {
  unsigned u = __builtin_bit_cast(unsigned, x);
  unsigned r = (u + 0x7fffu + ((u >> 16) & 1u)) >> 16;
  return (unsigned short)r;
}
// single-instruction packed f32->bf16 (RTNE, same as f2bf)
__device__ __forceinline__ int cvtpk(float lo, float hi) {
  int r;
  asm("v_cvt_pk_bf16_f32 %0, %1, %2" : "=v"(r) : "v"(lo), "v"(hi));
  return r;
}
__device__ __forceinline__ i32x4 pack8bf_pk(f32x4 a, f32x4 b) {
  i32x4 r;
  r.x = cvtpk(a.x, a.y); r.y = cvtpk(a.z, a.w);
  r.z = cvtpk(b.x, b.y); r.w = cvtpk(b.z, b.w);
  return r;
}
__device__ __forceinline__ float waveRed(float v) {
#pragma unroll
  for (int o = 32; o > 0; o >>= 1) v += __shfl_down(v, o);
  return v;
}

#define MFMA(acc, A, B) \
  acc = __builtin_amdgcn_mfma_f32_16x16x32_bf16( \
      __builtin_bit_cast(bf16x8, A), __builtin_bit_cast(bf16x8, B), acc, 0, 0, 0)

// ---------------- pack frag table (16 KB-strided pair-tile chunks) ---------
__global__ void lamp_pack(const float* __restrict__ Bre, const float* __restrict__ Bim,
                          const float* __restrict__ Are, const float* __restrict__ Aim,
                          unsigned short* __restrict__ fr)
{
  int i = blockIdx.x * 256 + threadIdx.x;       // 512*256 = 131072 = 16*8192
  int jj = i & 7, l = (i >> 3) & 63;
  int j = (i >> 9) & 15;                        // slot within chunk (0..15)
  int p = i >> 13;                              // chunk (0..15)
  float v = 0.f;
  if (j < 8) {
    int nt = 2*p + (j >> 2);
    int mat = (j >> 1) & 1;
    int ks = j & 1;
    int k = ks*32 + (l >> 4)*8 + jj;
    int n = nt*16 + (l & 15);
    v = (k < KK) ? (mat ? Bim[n*KK + k] : Bre[n*KK + k]) : 0.f;
  } else if (j < 14) {
    int jp = j - 8;
    int ct = jp >> 1, m = jp & 1;
    int k = p*32 + (l >> 4)*8 + jj;
    int c = ct*16 + (l & 15);
    v = m ? Aim[k*KK + c] : Are[k*KK + c];
  }
  fr[i] = f2bf(v);
}

// ---------------- sigma ----------------
__global__ void lamp_sig(const float* __restrict__ zr, const float* __restrict__ zi,
                         float* __restrict__ part)
{
  const int n4 = BATCH_*KK/4;
  const f32x4* a = (const f32x4*)zr; const f32x4* b = (const f32x4*)zi;
  float s = 0.f;
  for (int i = blockIdx.x*blockDim.x + threadIdx.x; i < n4; i += gridDim.x*blockDim.x) {
    f32x4 x = a[i]; s += x.x*x.x + x.y*x.y + x.z*x.z + x.w*x.w;
    f32x4 y = b[i]; s += y.x*y.x + y.y*y.y + y.z*y.z + y.w*y.w;
  }
  __shared__ float red[4];
  s = waveRed(s);
  int wave = threadIdx.x >> 6, lane = threadIdx.x & 63;
  if (lane == 0) red[wave] = s;
  __syncthreads();
  if (threadIdx.x == 0) part[blockIdx.x] = red[0]+red[1]+red[2]+red[3];
}

__global__ void lamp_sigfin(const float* __restrict__ part, float* __restrict__ sig)
{
  float s = part[threadIdx.x];   // 256 partials
  __shared__ float red[4];
  s = waveRed(s);
  int wave = threadIdx.x >> 6, lane = threadIdx.x & 63;
  if (lane == 0) red[wave] = s;
  __syncthreads();
  if (threadIdx.x == 0) sig[0] = sqrtf(red[0]+red[1]+red[2]+red[3]) / sqrtf((float)KK);
}

// ---------------- main fused kernel (R12) ----------------------------------
// R10 base (LDS frag staging, cvt_pk, plain stores, setprio; NO H-prefetch —
// R11 showed it regresses) + DEPTH-2 staging with triple-buffered LDS:
// iter t stages chunk t+2, reads chunk t. vmcnt ledger (issue order per
// iter: 4 H, 4 stage, 4 stores): barrier vmcnt(8) leaves {stage(t+2),
// stores(t)} in flight and guarantees stage(t+1) retired (older than the
// newest 8). Tail t>=14: vmcnt(4) (no stage issued; must pin stage(15)).
__global__ __launch_bounds__(256, 3) void lamp_main(
    const float* __restrict__ zre, const float* __restrict__ zim,
    const float* __restrict__ Hre, const float* __restrict__ Him,
    const unsigned short* __restrict__ fr,
    const float* __restrict__ sigp, const float* __restrict__ theta,
    float* __restrict__ out, float* __restrict__ bpart)
{
  __shared__ __align__(16) i32x4 fb[3][1024];   // 3 x 16384 B = 48 KB

  const int tid = threadIdx.x;
  const int wave = tid >> 6, lane = tid & 63;
  const int l15 = lane & 15, lg = lane >> 4;
  const int rbase = blockIdx.x * 64 + wave * 16;
  const int myrow = rbase + l15;
  const int phase = blockIdx.x & 15;
  const char* frc = (const char*)fr;

#define STAGE(bi, pp) do { \
    const char* gsrc_ = frc + (size_t)(pp)*16384 + wave*4096 + lane*16; \
    char* ldst_ = ((char*)&fb[bi][0]) + wave*4096 + lane*16; \
    _Pragma("unroll") \
    for (int s_ = 0; s_ < 4; ++s_) \
      __builtin_amdgcn_global_load_lds( \
          (const __attribute__((address_space(1))) void*)(gsrc_ + s_*1024), \
          (__attribute__((address_space(3))) void*)(ldst_ + s_*1024), 16, 0, 0); \
    asm volatile("" ::: "memory"); \
  } while (0)

  const float t0 = theta[0], t1 = theta[1], t2 = theta[2];
  const float sigma = sigp[0];
  const float s2 = (t0 * sigma) * (t0 * sigma);
  const float inv_s2 = 1.0f / s2;
  const float nhalf_inv_s2 = -0.5f * inv_s2;

  // z fragments (B operand of GEMM1'), K padded 48->64
  i32x4 zr[2], zi[2];
  {
    const float* pr = zre + (size_t)myrow * KK;
    const float* pi = zim + (size_t)myrow * KK;
#pragma unroll
    for (int ks = 0; ks < 2; ++ks) {
      const int k0 = ks*32 + lg*8;
      f32x4 a0 = {0,0,0,0}, a1 = {0,0,0,0}, b0 = {0,0,0,0}, b1 = {0,0,0,0};
      if (k0 < KK) {
        a0 = *(const f32x4*)(pr + k0); a1 = *(const f32x4*)(pr + k0 + 4);
        b0 = *(const f32x4*)(pi + k0); b1 = *(const f32x4*)(pi + k0 + 4);
      }
      zr[ks] = pack8bf_pk(a0, a1);
      zi[ks] = pack8bf_pk(b0, b1);
    }
  }

  const float* hrB = Hre + (size_t)myrow * NN + lg*4;
  const float* hiB = Him + (size_t)myrow * NN + lg*4;
  float* oRB = out + OFF_HHRE + (size_t)myrow * NN + lg*4;
  float* oIB = out + OFF_HHIM + (size_t)myrow * NN + lg*4;

  f32x4 ahR[3], ahI[3];
#pragma unroll
  for (int c = 0; c < 3; ++c) { ahR[c] = (f32x4){0,0,0,0}; ahI[c] = (f32x4){0,0,0,0}; }

  float dsr = 0.f, dsi = 0.f;
  const bool hi2 = (lg >= 2);
  const int srcA = l15 + ((lane & 16) << 1);
  const int srcB = srcA + 16;

  // prologue: stage chunks 0 and 1 (depth-2 pipeline), full drain once
  STAGE(0, phase);
  STAGE(1, (phase + 1) & 15);
  asm volatile("s_waitcnt vmcnt(0)" ::: "memory");
  __builtin_amdgcn_s_barrier();

  // buffer index t%3 tracked incrementally (avoid runtime modulo)
  int cur = 0, nxt2 = 2;

#pragma unroll 1
  for (int t = 0; t < 16; ++t) {
    const int p = (phase + t) & 15;

    // H loads first (deepest latency; compiler auto-waits before the add,
    // which also retires stage(t) — older in the VMEM queue)
    f32x4 hR0 = *(const f32x4*)(hrB + 32*p);
    f32x4 hR1 = *(const f32x4*)(hrB + 32*p + 16);
    f32x4 hI0 = *(const f32x4*)(hiB + 32*p);
    f32x4 hI1 = *(const f32x4*)(hiB + 32*p + 16);

    // depth-2 stage: chunk t+2 into buffer (t+2)%3
    if (t < 14) STAGE(nxt2, (phase + t + 2) & 15);

    const i32x4* fbc = &fb[cur][0];
    i32x4 nzi0 = zi[0] ^ 0x80008000, nzi1 = zi[1] ^ 0x80008000;

    // ---- GEMM1' tiles (frags from LDS buffer cur; stage(t) retired by
    // the vmcnt at barrier t-1) ----
    f32x4 aR0 = (f32x4){0,0,0,0}, aI0 = (f32x4){0,0,0,0};
    f32x4 aR1 = (f32x4){0,0,0,0}, aI1 = (f32x4){0,0,0,0};
    {
      i32x4 b0 = fbc[0*64 + lane];
      i32x4 b1 = fbc[1*64 + lane];
      i32x4 c0 = fbc[2*64 + lane];
      i32x4 c1 = fbc[3*64 + lane];
      i32x4 d0 = fbc[4*64 + lane];
      i32x4 d1 = fbc[5*64 + lane];
      i32x4 e0 = fbc[6*64 + lane];
      i32x4 e1 = fbc[7*64 + lane];
      __builtin_amdgcn_s_setprio(1);
      MFMA(aR0, b0, zr[0]); MFMA(aR0, b1, zr[1]);
      MFMA(aR0, c0, nzi0);  MFMA(aR0, c1, nzi1);
      MFMA(aI0, b0, zi[0]); MFMA(aI0, b1, zi[1]);
      MFMA(aI0, c0, zr[0]); MFMA(aI0, c1, zr[1]);
      MFMA(aR1, d0, zr[0]); MFMA(aR1, d1, zr[1]);
      MFMA(aR1, e0, nzi0);  MFMA(aR1, e1, nzi1);
      MFMA(aI1, d0, zi[0]); MFMA(aI1, d1, zi[1]);
      MFMA(aI1, e0, zr[0]); MFMA(aI1, e1, zr[1]);
      __builtin_amdgcn_s_setprio(0);
    }

    // ---- fused elementwise: R = H + Z, shrink, deriv ----
    f32x4 re0 = aR0 + hR0, im0 = aI0 + hI0;
    f32x4 re1 = aR1 + hR1, im1 = aI1 + hI1;
    f32x4 hhr0, hhi0, hhr1, hhi1;
#pragma unroll
    for (int c = 0; c < 4; ++c) {
      float x;
      x = re0[c]; { float e = __expf(x*x*nhalf_inv_s2); float te = t2*e;
        hhr0[c] = t1*x + x*te; dsr += t1 + te*(1.f - x*x*inv_s2); }
      x = im0[c]; { float e = __expf(x*x*nhalf_inv_s2); float te = t2*e;
        hhi0[c] = t1*x + x*te; dsi += t1 + te*(1.f - x*x*inv_s2); }
      x = re1[c]; { float e = __expf(x*x*nhalf_inv_s2); float te = t2*e;
        hhr1[c] = t1*x + x*te; dsr += t1 + te*(1.f - x*x*inv_s2); }
      x = im1[c]; { float e = __expf(x*x*nhalf_inv_s2); float te = t2*e;
        hhi1[c] = t1*x + x*te; dsi += t1 + te*(1.f - x*x*inv_s2); }
    }

    // ---- 4-lane exchange: acc row-slices -> GEMM2' B-operand frags ----
    {
      f32x4 selR, selI;
#pragma unroll
      for (int c = 0; c < 4; ++c) {
        selR[c] = hi2 ? hhr1[c] : hhr0[c];
        selI[c] = hi2 ? hhi1[c] : hhi0[c];
      }
      f32x4 w0, w1, v0, v1;
#pragma unroll
      for (int c = 0; c < 4; ++c) {
        w0[c] = __shfl(selR[c], srcA, 64);
        w1[c] = __shfl(selR[c], srcB, 64);
        v0[c] = __shfl(selI[c], srcA, 64);
        v1[c] = __shfl(selI[c], srcB, 64);
      }
      i32x4 hhRf = pack8bf_pk(w0, w1);
      i32x4 hhIf = pack8bf_pk(v0, v1);

      __builtin_amdgcn_s_setprio(1);
#pragma unroll
      for (int ct = 0; ct < 3; ++ct) {
        i32x4 par = fbc[(8 + 2*ct)*64 + lane];
        i32x4 pai = fbc[(9 + 2*ct)*64 + lane];
        i32x4 nai = pai ^ 0x80008000;
        MFMA(ahR[ct], par, hhRf);
        MFMA(ahR[ct], nai, hhIf);
        MFMA(ahI[ct], pai, hhRf);
        MFMA(ahI[ct], par, hhIf);
      }
      __builtin_amdgcn_s_setprio(0);
    }

    // ---- Hh stores LAST in VMEM order ----
    asm volatile("" ::: "memory");
    *(f32x4*)(oRB + 32*p)      = hhr0;
    *(f32x4*)(oRB + 32*p + 16) = hhr1;
    *(f32x4*)(oIB + 32*p)      = hhi0;
    *(f32x4*)(oIB + 32*p + 16) = hhi1;

    // counted barrier: steady state vmcnt(8) keeps {stage(t+2), stores(t)}
    // in flight, retires stage(t+1) and older. Tail: vmcnt(4).
    if (t < 14) {
      asm volatile("s_waitcnt vmcnt(8)" ::: "memory");
    } else {
      asm volatile("s_waitcnt vmcnt(4)" ::: "memory");
    }
    __builtin_amdgcn_s_barrier();
    __builtin_amdgcn_sched_barrier(0);

    cur = (cur == 2) ? 0 : cur + 1;
    nxt2 = (nxt2 == 2) ? 0 : nxt2 + 1;
  }

  // epilogue: h stored as per-lane f32x4 row slices
#pragma unroll
  for (int ct = 0; ct < 3; ++ct) {
    *(f32x4*)(out + (size_t)myrow*KK + ct*16 + lg*4) = ahR[ct];
    *(f32x4*)(out + (size_t)(BATCH_*KK) + (size_t)myrow*KK + ct*16 + lg*4) = ahI[ct];
  }

  float rr = waveRed(dsr), ri = waveRed(dsi);
  if (lane == 0) {
    const int w = blockIdx.x * 4 + wave;
    bpart[2*w]     = rr;
    bpart[2*w + 1] = ri;
  }
#undef STAGE
}

// ---------------- b reduce (4096 wave-partials) ----------------
__global__ void lamp_bred(const float* __restrict__ bpart, float* __restrict__ bval)
{
  float sr = 0.f, si = 0.f;
  for (int m = threadIdx.x; m < 4096; m += 256) { sr += bpart[2*m]; si += bpart[2*m + 1]; }
  __shared__ float red[8];
  sr = waveRed(sr); si = waveRed(si);
  int wave = threadIdx.x >> 6, lane = threadIdx.x & 63;
  if (lane == 0) { red[wave] = sr; red[4 + wave] = si; }
  __syncthreads();
  if (threadIdx.x == 0) {
    bval[0] = (red[0]+red[1]+red[2]+red[3]) / (float)KK;
    bval[1] = (red[4]+red[5]+red[6]+red[7]) / (float)KK;
  }
}

// ---------------- z_new (in-place over parked h) ----------------
__global__ void lamp_znew(const float* __restrict__ ur, const float* __restrict__ ui,
                          const float* __restrict__ zr, const float* __restrict__ zi,
                          const float* __restrict__ bval, float* __restrict__ out)
{
  const float br = bval[0], bi = bval[1];
  const int n4 = BATCH_*KK/4;
  const f32x4* u4r = (const f32x4*)ur; const f32x4* u4i = (const f32x4*)ui;
  const f32x4* z4r = (const f32x4*)zr; const f32x4* z4i = (const f32x4*)zi;
  f32x4* o4r = (f32x4*)out;
  f32x4* o4i = (f32x4*)(out + BATCH_*KK);
  for (int i = blockIdx.x*blockDim.x + threadIdx.x; i < n4; i += gridDim.x*blockDim.x) {
    f32x4 h = o4r[i];
    o4r[i] = u4r[i] - h + br * z4r[i];
    f32x4 h2 = o4i[i];
    o4i[i] = u4i[i] - h2 + bi * z4i[i];
  }
}

extern "C" void kernel_launch(void* const* d_in, const int* in_sizes, int n_in,
                              void* d_out, int out_size, void* d_ws, size_t ws_size,
                              hipStream_t stream)
{
  const float* ur  = (const float*)d_in[0];
  const float* ui  = (const float*)d_in[1];
  const float* zr  = (const float*)d_in[2];
  const float* zi  = (const float*)d_in[3];
  const float* Hr  = (const float*)d_in[4];
  const float* Hi  = (const float*)d_in[5];
  const float* Bre = (const float*)d_in[6];
  const float* Bim = (const float*)d_in[7];
  const float* Are = (const float*)d_in[8];
  const float* Aim = (const float*)d_in[9];
  const float* th  = (const float*)d_in[10];
  float* out = (float*)d_out;
  char* ws = (char*)d_ws;
  unsigned short* fr = (unsigned short*)(ws + WS_FR);
  float* sigp  = (float*)(ws + WS_SIGP);
  float* sigv  = (float*)(ws + WS_SIGMA);
  float* bpart = (float*)(ws + WS_BPART);
  float* bval  = (float*)(ws + WS_BVAL);

  hipLaunchKernelGGL(lamp_pack,   dim3(512),  dim3(256), 0, stream, Bre, Bim, Are, Aim, fr);
  hipLaunchKernelGGL(lamp_sig,    dim3(256),  dim3(256), 0, stream, zr, zi, sigp);
  hipLaunchKernelGGL(lamp_sigfin, dim3(1),    dim3(256), 0, stream, sigp, sigv);
  hipLaunchKernelGGL(lamp_main,   dim3(1024), dim3(256), 0, stream,
                     zr, zi, Hr, Hi, fr, sigv, th, out, bpart);
  hipLaunchKernelGGL(lamp_bred,   dim3(1),    dim3(256), 0, stream, bpart, bval);
  hipLaunchKernelGGL(lamp_znew,   dim3(1024), dim3(256), 0, stream, ur, ui, zr, zi, bval, out);
}

// Round 13
// 160.132 us; speedup vs baseline: 2.4413x; 1.0336x over previous
//
#include <hip/hip_runtime.h>
#include <math.h>

#define BATCH_ 65536
#define NN 512
#define KK 48
#define OFF_HHRE (2*BATCH_*KK)            // 6291456
#define OFF_HHIM (OFF_HHRE + BATCH_*NN)   // 39845888

typedef float f32x4 __attribute__((ext_vector_type(4)));
typedef int   i32x4 __attribute__((ext_vector_type(4)));
typedef short bf16x8 __attribute__((ext_vector_type(8)));

// ---- ws layout (byte offsets) ----
#define WS_FR    0u         // 16 chunks x 16384 B = 262144 B
#define WS_SIGP  262144u    // 256 f32
#define WS_SIGMA 263168u    // 1 f32
#define WS_BPART 264192u    // 4096*2 f32 = 32 KB
#define WS_BVAL  296960u    // 2 f32

__device__ __forceinline__ unsigned short f2bf(float x) {
  unsigned u = __builtin_bit_cast(unsigned, x);
  unsigned r = (u + 0x7fffu + ((u >> 16) & 1u)) >> 16;
  return (unsigned short)r;
}
// single-instruction packed f32->bf16 (RTNE, same as f2bf)
__device__ __forceinline__ int cvtpk(float lo, float hi) {
  int r;
  asm("v_cvt_pk_bf16_f32 %0, %1, %2" : "=v"(r) : "v"(lo), "v"(hi));
  return r;
}
__device__ __forceinline__ i32x4 pack8bf_pk(f32x4 a, f32x4 b) {
  i32x4 r;
  r.x = cvtpk(a.x, a.y); r.y = cvtpk(a.z, a.w);
  r.z = cvtpk(b.x, b.y); r.w = cvtpk(b.z, b.w);
  return r;
}
__device__ __forceinline__ float waveRed(float v) {
#pragma unroll
  for (int o = 32; o > 0; o >>= 1) v += __shfl_down(v, o);
  return v;
}

#define MFMA(acc, A, B) \
  acc = __builtin_amdgcn_mfma_f32_16x16x32_bf16( \
      __builtin_bit_cast(bf16x8, A), __builtin_bit_cast(bf16x8, B), acc, 0, 0, 0)

// ------- fused: pack frag table (blocks 0..511) + sigma partials (512..767)
__global__ void lamp_packsig(const float* __restrict__ Bre, const float* __restrict__ Bim,
                             const float* __restrict__ Are, const float* __restrict__ Aim,
                             const float* __restrict__ zr, const float* __restrict__ zi,
                             unsigned short* __restrict__ fr, float* __restrict__ part)
{
  if (blockIdx.x < 512) {
    int i = blockIdx.x * 256 + threadIdx.x;     // 512*256 = 131072 = 16*8192
    int jj = i & 7, l = (i >> 3) & 63;
    int j = (i >> 9) & 15;                      // slot within chunk (0..15)
    int p = i >> 13;                            // chunk (0..15)
    float v = 0.f;
    if (j < 8) {
      int nt = 2*p + (j >> 2);
      int mat = (j >> 1) & 1;
      int ks = j & 1;
      int k = ks*32 + (l >> 4)*8 + jj;
      int n = nt*16 + (l & 15);
      v = (k < KK) ? (mat ? Bim[n*KK + k] : Bre[n*KK + k]) : 0.f;
    } else if (j < 14) {
      int jp = j - 8;
      int ct = jp >> 1, m = jp & 1;
      int k = p*32 + (l >> 4)*8 + jj;
      int c = ct*16 + (l & 15);
      v = m ? Aim[k*KK + c] : Are[k*KK + c];
    }
    fr[i] = f2bf(v);
  } else {
    const int bid = blockIdx.x - 512;           // 256 sigma blocks
    const int n4 = BATCH_*KK/4;
    const f32x4* a = (const f32x4*)zr; const f32x4* b = (const f32x4*)zi;
    float s = 0.f;
    for (int i = bid*256 + threadIdx.x; i < n4; i += 256*256) {
      f32x4 x = a[i]; s += x.x*x.x + x.y*x.y + x.z*x.z + x.w*x.w;
      f32x4 y = b[i]; s += y.x*y.x + y.y*y.y + y.z*y.z + y.w*y.w;
    }
    __shared__ float red[4];
    s = waveRed(s);
    int wave = threadIdx.x >> 6, lane = threadIdx.x & 63;
    if (lane == 0) red[wave] = s;
    __syncthreads();
    if (threadIdx.x == 0) part[bid] = red[0]+red[1]+red[2]+red[3];
  }
}

__global__ void lamp_sigfin(const float* __restrict__ part, float* __restrict__ sig)
{
  float s = part[threadIdx.x];   // 256 partials
  __shared__ float red[4];
  s = waveRed(s);
  int wave = threadIdx.x >> 6, lane = threadIdx.x & 63;
  if (lane == 0) red[wave] = s;
  __syncthreads();
  if (threadIdx.x == 0) sig[0] = sqrtf(red[0]+red[1]+red[2]+red[3]) / sqrtf((float)KK);
}

// ---------------- main fused kernel (R13) ----------------------------------
// R12 structure (depth-2 triple-buffered LDS staging, counted vmcnt(8)
// barrier, cvt_pk, plain stores, setprio) with __launch_bounds__(256,4):
// cap VGPR at 64 to unlock 4 waves/SIMD (was ~70-76 -> 3 waves/SIMD, 25%
// occupancy). Hot values (acc, z frags) fit; only cold values can spill.
// Revert trigger: FETCH/WRITE balloon = spill traffic.
__global__ __launch_bounds__(256, 4) void lamp_main(
    const float* __restrict__ zre, const float* __restrict__ zim,
    const float* __restrict__ Hre, const float* __restrict__ Him,
    const unsigned short* __restrict__ fr,
    const float* __restrict__ sigp, const float* __restrict__ theta,
    float* __restrict__ out, float* __restrict__ bpart)
{
  __shared__ __align__(16) i32x4 fb[3][1024];   // 3 x 16384 B = 48 KB

  const int tid = threadIdx.x;
  const int wave = tid >> 6, lane = tid & 63;
  const int l15 = lane & 15, lg = lane >> 4;
  const int rbase = blockIdx.x * 64 + wave * 16;
  const int myrow = rbase + l15;
  const int phase = blockIdx.x & 15;
  const char* frc = (const char*)fr;

#define STAGE(bi, pp) do { \
    const char* gsrc_ = frc + (size_t)(pp)*16384 + wave*4096 + lane*16; \
    char* ldst_ = ((char*)&fb[bi][0]) + wave*4096 + lane*16; \
    _Pragma("unroll") \
    for (int s_ = 0; s_ < 4; ++s_) \
      __builtin_amdgcn_global_load_lds( \
          (const __attribute__((address_space(1))) void*)(gsrc_ + s_*1024), \
          (__attribute__((address_space(3))) void*)(ldst_ + s_*1024), 16, 0, 0); \
    asm volatile("" ::: "memory"); \
  } while (0)

  const float t0 = theta[0], t1 = theta[1], t2 = theta[2];
  const float sigma = sigp[0];
  const float s2 = (t0 * sigma) * (t0 * sigma);
  const float inv_s2 = 1.0f / s2;
  const float nhalf_inv_s2 = -0.5f * inv_s2;

  // z fragments (B operand of GEMM1'), K padded 48->64
  i32x4 zr[2], zi[2];
  {
    const float* pr = zre + (size_t)myrow * KK;
    const float* pi = zim + (size_t)myrow * KK;
#pragma unroll
    for (int ks = 0; ks < 2; ++ks) {
      const int k0 = ks*32 + lg*8;
      f32x4 a0 = {0,0,0,0}, a1 = {0,0,0,0}, b0 = {0,0,0,0}, b1 = {0,0,0,0};
      if (k0 < KK) {
        a0 = *(const f32x4*)(pr + k0); a1 = *(const f32x4*)(pr + k0 + 4);
        b0 = *(const f32x4*)(pi + k0); b1 = *(const f32x4*)(pi + k0 + 4);
      }
      zr[ks] = pack8bf_pk(a0, a1);
      zi[ks] = pack8bf_pk(b0, b1);
    }
  }

  const float* hrB = Hre + (size_t)myrow * NN + lg*4;
  const float* hiB = Him + (size_t)myrow * NN + lg*4;
  float* oRB = out + OFF_HHRE + (size_t)myrow * NN + lg*4;
  float* oIB = out + OFF_HHIM + (size_t)myrow * NN + lg*4;

  f32x4 ahR[3], ahI[3];
#pragma unroll
  for (int c = 0; c < 3; ++c) { ahR[c] = (f32x4){0,0,0,0}; ahI[c] = (f32x4){0,0,0,0}; }

  float dsr = 0.f, dsi = 0.f;
  const bool hi2 = (lg >= 2);
  const int srcA = l15 + ((lane & 16) << 1);
  const int srcB = srcA + 16;

  // prologue: stage chunks 0 and 1 (depth-2 pipeline), full drain once
  STAGE(0, phase);
  STAGE(1, (phase + 1) & 15);
  asm volatile("s_waitcnt vmcnt(0)" ::: "memory");
  __builtin_amdgcn_s_barrier();

  // buffer index t%3 tracked incrementally (avoid runtime modulo)
  int cur = 0, nxt2 = 2;

#pragma unroll 1
  for (int t = 0; t < 16; ++t) {
    const int p = (phase + t) & 15;

    // H loads first (deepest latency)
    f32x4 hR0 = *(const f32x4*)(hrB + 32*p);
    f32x4 hR1 = *(const f32x4*)(hrB + 32*p + 16);
    f32x4 hI0 = *(const f32x4*)(hiB + 32*p);
    f32x4 hI1 = *(const f32x4*)(hiB + 32*p + 16);

    // depth-2 stage: chunk t+2 into buffer (t+2)%3
    if (t < 14) STAGE(nxt2, (phase + t + 2) & 15);

    const i32x4* fbc = &fb[cur][0];
    i32x4 nzi0 = zi[0] ^ 0x80008000, nzi1 = zi[1] ^ 0x80008000;

    // ---- GEMM1' tiles (frags from LDS buffer cur) ----
    f32x4 aR0 = (f32x4){0,0,0,0}, aI0 = (f32x4){0,0,0,0};
    f32x4 aR1 = (f32x4){0,0,0,0}, aI1 = (f32x4){0,0,0,0};
    {
      i32x4 b0 = fbc[0*64 + lane];
      i32x4 b1 = fbc[1*64 + lane];
      i32x4 c0 = fbc[2*64 + lane];
      i32x4 c1 = fbc[3*64 + lane];
      i32x4 d0 = fbc[4*64 + lane];
      i32x4 d1 = fbc[5*64 + lane];
      i32x4 e0 = fbc[6*64 + lane];
      i32x4 e1 = fbc[7*64 + lane];
      __builtin_amdgcn_s_setprio(1);
      MFMA(aR0, b0, zr[0]); MFMA(aR0, b1, zr[1]);
      MFMA(aR0, c0, nzi0);  MFMA(aR0, c1, nzi1);
      MFMA(aI0, b0, zi[0]); MFMA(aI0, b1, zi[1]);
      MFMA(aI0, c0, zr[0]); MFMA(aI0, c1, zr[1]);
      MFMA(aR1, d0, zr[0]); MFMA(aR1, d1, zr[1]);
      MFMA(aR1, e0, nzi0);  MFMA(aR1, e1, nzi1);
      MFMA(aI1, d0, zi[0]); MFMA(aI1, d1, zi[1]);
      MFMA(aI1, e0, zr[0]); MFMA(aI1, e1, zr[1]);
      __builtin_amdgcn_s_setprio(0);
    }

    // ---- fused elementwise: R = H + Z, shrink, deriv ----
    f32x4 re0 = aR0 + hR0, im0 = aI0 + hI0;
    f32x4 re1 = aR1 + hR1, im1 = aI1 + hI1;
    f32x4 hhr0, hhi0, hhr1, hhi1;
#pragma unroll
    for (int c = 0; c < 4; ++c) {
      float x;
      x = re0[c]; { float e = __expf(x*x*nhalf_inv_s2); float te = t2*e;
        hhr0[c] = t1*x + x*te; dsr += t1 + te*(1.f - x*x*inv_s2); }
      x = im0[c]; { float e = __expf(x*x*nhalf_inv_s2); float te = t2*e;
        hhi0[c] = t1*x + x*te; dsi += t1 + te*(1.f - x*x*inv_s2); }
      x = re1[c]; { float e = __expf(x*x*nhalf_inv_s2); float te = t2*e;
        hhr1[c] = t1*x + x*te; dsr += t1 + te*(1.f - x*x*inv_s2); }
      x = im1[c]; { float e = __expf(x*x*nhalf_inv_s2); float te = t2*e;
        hhi1[c] = t1*x + x*te; dsi += t1 + te*(1.f - x*x*inv_s2); }
    }

    // ---- 4-lane exchange: acc row-slices -> GEMM2' B-operand frags ----
    {
      f32x4 selR, selI;
#pragma unroll
      for (int c = 0; c < 4; ++c) {
        selR[c] = hi2 ? hhr1[c] : hhr0[c];
        selI[c] = hi2 ? hhi1[c] : hhi0[c];
      }
      f32x4 w0, w1, v0, v1;
#pragma unroll
      for (int c = 0; c < 4; ++c) {
        w0[c] = __shfl(selR[c], srcA, 64);
        w1[c] = __shfl(selR[c], srcB, 64);
        v0[c] = __shfl(selI[c], srcA, 64);
        v1[c] = __shfl(selI[c], srcB, 64);
      }
      i32x4 hhRf = pack8bf_pk(w0, w1);
      i32x4 hhIf = pack8bf_pk(v0, v1);

      __builtin_amdgcn_s_setprio(1);
#pragma unroll
      for (int ct = 0; ct < 3; ++ct) {
        i32x4 par = fbc[(8 + 2*ct)*64 + lane];
        i32x4 pai = fbc[(9 + 2*ct)*64 + lane];
        i32x4 nai = pai ^ 0x80008000;
        MFMA(ahR[ct], par, hhRf);
        MFMA(ahR[ct], nai, hhIf);
        MFMA(ahI[ct], pai, hhRf);
        MFMA(ahI[ct], par, hhIf);
      }
      __builtin_amdgcn_s_setprio(0);
    }

    // ---- Hh stores LAST in VMEM order ----
    asm volatile("" ::: "memory");
    *(f32x4*)(oRB + 32*p)      = hhr0;
    *(f32x4*)(oRB + 32*p + 16) = hhr1;
    *(f32x4*)(oIB + 32*p)      = hhi0;
    *(f32x4*)(oIB + 32*p + 16) = hhi1;

    // counted barrier: steady state vmcnt(8) keeps {stage(t+2), stores(t)}
    // in flight, retires stage(t+1) and older. Tail: vmcnt(4).
    if (t < 14) {
      asm volatile("s_waitcnt vmcnt(8)" ::: "memory");
    } else {
      asm volatile("s_waitcnt vmcnt(4)" ::: "memory");
    }
    __builtin_amdgcn_s_barrier();
    __builtin_amdgcn_sched_barrier(0);

    cur = (cur == 2) ? 0 : cur + 1;
    nxt2 = (nxt2 == 2) ? 0 : nxt2 + 1;
  }

  // epilogue: h stored as per-lane f32x4 row slices
#pragma unroll
  for (int ct = 0; ct < 3; ++ct) {
    *(f32x4*)(out + (size_t)myrow*KK + ct*16 + lg*4) = ahR[ct];
    *(f32x4*)(out + (size_t)(BATCH_*KK) + (size_t)myrow*KK + ct*16 + lg*4) = ahI[ct];
  }

  float rr = waveRed(dsr), ri = waveRed(dsi);
  if (lane == 0) {
    const int w = blockIdx.x * 4 + wave;
    bpart[2*w]     = rr;
    bpart[2*w + 1] = ri;
  }
#undef STAGE
}

// ---------------- b reduce (4096 wave-partials) ----------------
__global__ void lamp_bred(const float* __restrict__ bpart, float* __restrict__ bval)
{
  float sr = 0.f, si = 0.f;
  for (int m = threadIdx.x; m < 4096; m += 256) { sr += bpart[2*m]; si += bpart[2*m + 1]; }
  __shared__ float red[8];
  sr = waveRed(sr); si = waveRed(si);
  int wave = threadIdx.x >> 6, lane = threadIdx.x & 63;
  if (lane == 0) { red[wave] = sr; red[4 + wave] = si; }
  __syncthreads();
  if (threadIdx.x == 0) {
    bval[0] = (red[0]+red[1]+red[2]+red[3]) / (float)KK;
    bval[1] = (red[4]+red[5]+red[6]+red[7]) / (float)KK;
  }
}

// ---------------- z_new (in-place over parked h) ----------------
__global__ void lamp_znew(const float* __restrict__ ur, const float* __restrict__ ui,
                          const float* __restrict__ zr, const float* __restrict__ zi,
                          const float* __restrict__ bval, float* __restrict__ out)
{
  const float br = bval[0], bi = bval[1];
  const int n4 = BATCH_*KK/4;
  const f32x4* u4r = (const f32x4*)ur; const f32x4* u4i = (const f32x4*)ui;
  const f32x4* z4r = (const f32x4*)zr; const f32x4* z4i = (const f32x4*)zi;
  f32x4* o4r = (f32x4*)out;
  f32x4* o4i = (f32x4*)(out + BATCH_*KK);
  for (int i = blockIdx.x*blockDim.x + threadIdx.x; i < n4; i += gridDim.x*blockDim.x) {
    f32x4 h = o4r[i];
    o4r[i] = u4r[i] - h + br * z4r[i];
    f32x4 h2 = o4i[i];
    o4i[i] = u4i[i] - h2 + bi * z4i[i];
  }
}

extern "C" void kernel_launch(void* const* d_in, const int* in_sizes, int n_in,
                              void* d_out, int out_size, void* d_ws, size_t ws_size,
                              hipStream_t stream)
{
  const float* ur  = (const float*)d_in[0];
  const float* ui  = (const float*)d_in[1];
  const float* zr  = (const float*)d_in[2];
  const float* zi  = (const float*)d_in[3];
  const float* Hr  = (const float*)d_in[4];
  const float* Hi  = (const float*)d_in[5];
  const float* Bre = (const float*)d_in[6];
  const float* Bim = (const float*)d_in[7];
  const float* Are = (const float*)d_in[8];
  const float* Aim = (const float*)d_in[9];
  const float* th  = (const float*)d_in[10];
  float* out = (float*)d_out;
  char* ws = (char*)d_ws;
  unsigned short* fr = (unsigned short*)(ws + WS_FR);
  float* sigp  = (float*)(ws + WS_SIGP);
  float* sigv  = (float*)(ws + WS_SIGMA);
  float* bpart = (float*)(ws + WS_BPART);
  float* bval  = (float*)(ws + WS_BVAL);

  hipLaunchKernelGGL(lamp_packsig, dim3(768),  dim3(256), 0, stream,
                     Bre, Bim, Are, Aim, zr, zi, fr, sigp);
  hipLaunchKernelGGL(lamp_sigfin,  dim3(1),    dim3(256), 0, stream, sigp, sigv);
  hipLaunchKernelGGL(lamp_main,    dim3(1024), dim3(256), 0, stream,
                     zr, zi, Hr, Hi, fr, sigv, th, out, bpart);
  hipLaunchKernelGGL(lamp_bred,    dim3(1),    dim3(256), 0, stream, bpart, bval);
  hipLaunchKernelGGL(lamp_znew,    dim3(1024), dim3(256), 0, stream, ur, ui, zr, zi, bval, out);
}